// Round 7
// baseline (4499.010 us; speedup 1.0000x reference)
//
#include <hip/hip_runtime.h>
#include <cstddef>
#include <cstdint>

// Problem constants
#define B_ 64
#define T_ 128
#define N_ 64
#define D_ 64
#define Q_ 5
#define E_ 8
#define P_ 768
#define H_ 128

typedef _Float16 f16;
typedef _Float16 f16x2 __attribute__((ext_vector_type(2)));
typedef _Float16 f16x4 __attribute__((ext_vector_type(4)));
typedef _Float16 f16x8 __attribute__((ext_vector_type(8)));
typedef float f32x4 __attribute__((ext_vector_type(4)));

__device__ __forceinline__ float fast_sig(float x) {
  return 1.f / (1.f + __expf(-x));
}
__device__ __forceinline__ float fast_tanh(float x) {
  return 1.f - 2.f / (1.f + __expf(2.f * x));
}
__device__ __forceinline__ f16x8 splat8(f16 c) {
  return f16x8{c, c, c, c, c, c, c, c};
}

// ---------------------------------------------------------------------------
// K1: per-node MLPs -> qv (N,Q) and row-normalized ne (N,E). One block per n.
// ---------------------------------------------------------------------------
__global__ void k_mlps(const float* __restrict__ vpr,
                       const float* __restrict__ Wf1, const float* __restrict__ bf1,
                       const float* __restrict__ Wf2, const float* __restrict__ bf2,
                       const float* __restrict__ Wg1, const float* __restrict__ bg1,
                       const float* __restrict__ Wg2, const float* __restrict__ bg2,
                       float* __restrict__ qv, float* __restrict__ neb) {
  int n = blockIdx.x;
  int tid = threadIdx.x;  // 256
  __shared__ float v[P_];
  __shared__ float hf[H_];
  __shared__ float hg[H_];
  __shared__ float tmp[E_];

  for (int i = tid; i < P_; i += 256) v[i] = vpr[n * P_ + i];
  __syncthreads();

  if (tid < H_) {
    int j = tid;
    float a = bf1[j];
#pragma unroll 8
    for (int i = 0; i < P_; ++i) a += v[i] * Wf1[i * H_ + j];
    hf[j] = fmaxf(a, 0.f);
  } else {
    int j = tid - H_;
    float a = bg1[j];
#pragma unroll 8
    for (int i = 0; i < P_; ++i) a += v[i] * Wg1[i * H_ + j];
    hg[j] = fmaxf(a, 0.f);
  }
  __syncthreads();
  if (tid < Q_) {
    float a = bf2[tid];
    for (int j = 0; j < H_; ++j) a += hf[j] * Wf2[j * Q_ + tid];
    qv[n * Q_ + tid] = a;
  } else if (tid >= 8 && tid < 8 + E_) {
    int e = tid - 8;
    float a = bg2[e];
    for (int j = 0; j < H_; ++j) a += hg[j] * Wg2[j * E_ + e];
    tmp[e] = a;
  }
  __syncthreads();
  if (tid == 0) {
    float s = 0.f;
    for (int e = 0; e < E_; ++e) s += tmp[e] * tmp[e];
    float r = 1.f / sqrtf(s);
    for (int e = 0; e < E_; ++e) neb[n * E_ + e] = tmp[e] * r;
  }
}

// ---------------------------------------------------------------------------
// K2: adj row softmax -> adjP = f16x2{adj, adj*rarw}; per-node gate biases and
// rs-column weights (rank-1 fold of feature f=64). One block (64 thr) per n.
// ---------------------------------------------------------------------------
__global__ void k_meta(const float* __restrict__ neb, const float* __restrict__ qv,
                       const float* __restrict__ br, const float* __restrict__ bu,
                       const float* __restrict__ bc,
                       const float* __restrict__ Wr, const float* __restrict__ Wu,
                       const float* __restrict__ Wc, const float* __restrict__ rarw,
                       f16x2* __restrict__ adjP, float* __restrict__ brn,
                       float* __restrict__ bun, float* __restrict__ bcn,
                       float* __restrict__ WrsR, float* __restrict__ WrsU,
                       float* __restrict__ WrsC) {
  int n = blockIdx.x;
  int j = threadIdx.x;  // 64 = one wave
  float s = 0.f;
#pragma unroll
  for (int e = 0; e < E_; ++e) s += neb[n * E_ + e] * neb[j * E_ + e];
  float m = s;
  for (int off = 32; off; off >>= 1) m = fmaxf(m, __shfl_xor(m, off));
  float ex = __expf(s - m);
  float sum = ex;
  for (int off = 32; off; off >>= 1) sum += __shfl_xor(sum, off);
  float av = ex / sum;
  adjP[n * N_ + j] = f16x2{(f16)av, (f16)(av * rarw[n * N_ + j])};

  float pr = 0.f, pu = 0.f, pc = 0.f;
  float wr = 0.f, wu = 0.f, wc = 0.f;
#pragma unroll
  for (int q = 0; q < Q_; ++q) {
    float qq = qv[n * Q_ + q];
    pr += qq * br[q * D_ + j];
    pu += qq * bu[q * D_ + j];
    pc += qq * bc[q * D_ + j];
    wr += qq * Wr[((size_t)q * 129 + 64) * D_ + j];
    wu += qq * Wu[((size_t)q * 129 + 64) * D_ + j];
    wc += qq * Wc[((size_t)q * 129 + 64) * D_ + j];
  }
  brn[n * D_ + j] = pr;
  bun[n * D_ + j] = pu;
  bcn[n * D_ + j] = pc;
  WrsR[n * D_ + j] = wr;
  WrsU[n * D_ + j] = wu;
  WrsC[n * D_ + j] = wc;
}

// ---------------------------------------------------------------------------
// K3: pack shared gate weights into MFMA B-fragment order, fp16 (HW-verified
// in round 2 — do not change).
// frag id = ((g*5+q)*4+kt)*4+nt ; within frag lane l holds 8 f16:
//   B[k = 32*kt + 8*(l>>4) + e][col = 16*nt + (l&15)],  f = k + (k>=64)
// ---------------------------------------------------------------------------
__global__ void k_pack(const float* __restrict__ Wr, const float* __restrict__ Wu,
                       const float* __restrict__ Wc, f16* __restrict__ Wpk) {
  int bid = blockIdx.x;           // 240 = 3*5*4*4
  int nt = bid & 3;
  int kt = (bid >> 2) & 3;
  int q = (bid >> 4) % 5;
  int g = bid / 80;
  const float* W = (g == 0) ? Wr : ((g == 1) ? Wu : Wc);
  int l = threadIdx.x;            // 64
  int co = 16 * nt + (l & 15);
  f16* dst = Wpk + (size_t)bid * 512 + l * 8;
#pragma unroll
  for (int e = 0; e < 8; ++e) {
    int k = 32 * kt + 8 * (l >> 4) + e;
    int f = k + (k >= 64);
    dst[e] = (f16)W[((size_t)q * 129 + f) * D_ + co];
  }
}

// ---------------------------------------------------------------------------
// K4: var_total[b][n]
// ---------------------------------------------------------------------------
__global__ void k_vt(const float* __restrict__ mask, float* __restrict__ vt) {
  int b = blockIdx.x;
  int n = threadIdx.x;  // 64
  float s = 0.f;
  for (int t = 0; t < T_; ++t) s += mask[(b * T_ + t) * N_ + n];
  vt[b * N_ + n] = s;
}

// ---------------------------------------------------------------------------
// SEQ v8: TWO BATCHES PER BLOCK. Rounds 0-6 established: 4-wave/512-VGPR is
// the only register-feasible sync structure, and it is latency-bound (~60%
// stall at 1 wave/SIMD; LDS pipe 12%, VALU 27%, MFMA 11% of cycles).
// Cross-wave splits (r1-5) lose to exchange overhead; barrier merging (r6)
// is neutral. v8 doubles the INDEPENDENT work per wave instead: grid 32
// blocks, each runs batches b0,b1 phase-interleaved between the SAME 5
// barriers. Weights (240 regs), biases (48), qh, adjacency are batch-
// invariant -> shared; only h/upk/hrpk/prefetch duplicate (+~60 regs, peak
// ~445 <= 512; accumulators reused batch-sequentially). Per-batch LDS
// buffers; adjacency moved to a shared LDS table (frees 16 regs).
// LDS = 2*(combT 18432 + xA 9216 + actA 21504 + AP 11264 + rs/m/mr 768)
//       + qvS 1024 + adjS 16384 = 139,776 B.
// Decision rule: WRITE_SIZE clean but dur >= ~1800 -> stall is issue-
// throughput, pivot to packed-store instruction diet.
// ---------------------------------------------------------------------------
__global__ __launch_bounds__(256, 1) __attribute__((amdgpu_waves_per_eu(1, 1)))
void k_seq(const float* __restrict__ obs, const float* __restrict__ mask,
           const int* __restrict__ lengths, const float* __restrict__ ai,
           const f16x2* __restrict__ adjP,
           const float* __restrict__ brn, const float* __restrict__ bun,
           const float* __restrict__ bcn, const float* __restrict__ WrsR,
           const float* __restrict__ WrsU, const float* __restrict__ WrsC,
           const float* __restrict__ qv, const float* __restrict__ vt,
           const f16* __restrict__ Wpk, float* __restrict__ out) {
  // combT [feature k][node j] stride 72: rows 0..63 = x(d), 64..127 = h(d)
  __shared__ __align__(16) f16 combT[2][128 * 72];   // 36864 B
  __shared__ __align__(16) f16 xA[2][64 * 72];       // 18432 B
  __shared__ __align__(16) f16 actA[2][64 * 168];    // 43008 B  msg
  // AP [i][j] stride 88: A-matrix (P1..P2), then ALIASED as h_r [n][o]
  __shared__ __align__(16) f16 AP[2][64 * 88];       // 22528 B
  __shared__ __align__(16) f16 qvS[64 * 8];          //  1024 B
  __shared__ __align__(16) f16x2 adjS[64 * 64];      // 16384 B
  __shared__ __align__(16) float rsS[2][N_];
  __shared__ __align__(16) float mS[2][N_];
  __shared__ __align__(16) float mrS[2][N_];

  const int tid = threadIdx.x;
  const int b0 = 2 * blockIdx.x;
  const int lane = tid & 63;
  const int wv = tid >> 6;        // 4 waves
  const int lm = lane & 15;
  const int lq = lane >> 4;
  const int oc = 16 * wv + lm;    // this wave's output column

  const int pn = tid >> 2;        // staging / A-build row (0..63)
  const int pj = 16 * (tid & 3);  // 16-wide j / d block

  // ---- persistent weight fragments: [gate][kt][q], 240 VGPRs (shared) ----
  f16x8 wW[3][4][5];
#pragma unroll
  for (int g = 0; g < 3; ++g)
#pragma unroll
    for (int kt = 0; kt < 4; ++kt)
#pragma unroll
      for (int q = 0; q < 5; ++q)
        wW[g][kt][q] = *(const f16x8*)(Wpk +
            ((size_t)(((g * 5 + q) * 4 + kt) * 4 + wv) * 64 + lane) * 8);

  // ---- persistent biases / rs-fold weights (C-layout cells, shared) ----
  f16x2 bR[8], bU[8], bC[8], wRs[8], wUs[8], wCs[8];
#pragma unroll
  for (int mt = 0; mt < 4; ++mt)
#pragma unroll
    for (int ii = 0; ii < 2; ++ii) {
      int n0 = 16 * mt + 4 * lq + 2 * ii;
      bR[2 * mt + ii]  = f16x2{(f16)brn[n0 * D_ + oc],  (f16)brn[(n0 + 1) * D_ + oc]};
      bU[2 * mt + ii]  = f16x2{(f16)bun[n0 * D_ + oc],  (f16)bun[(n0 + 1) * D_ + oc]};
      bC[2 * mt + ii]  = f16x2{(f16)bcn[n0 * D_ + oc],  (f16)bcn[(n0 + 1) * D_ + oc]};
      wRs[2 * mt + ii] = f16x2{(f16)WrsR[n0 * D_ + oc], (f16)WrsR[(n0 + 1) * D_ + oc]};
      wUs[2 * mt + ii] = f16x2{(f16)WrsU[n0 * D_ + oc], (f16)WrsU[(n0 + 1) * D_ + oc]};
      wCs[2 * mt + ii] = f16x2{(f16)WrsC[n0 * D_ + oc], (f16)WrsC[(n0 + 1) * D_ + oc]};
    }

  // ---- adjacency -> LDS table (shared; batch-invariant) ----
  for (int i = tid; i < 64 * 64; i += 256) adjS[i] = adjP[i];

  // ---- qv staging (shared) ----
#pragma unroll
  for (int u2 = 0; u2 < 2; ++u2) {
    int idx = 2 * tid + u2;
    int n = idx >> 3, q = idx & 7;
    qvS[idx] = (q < Q_) ? (f16)qv[n * Q_ + q] : (f16)0.f;
  }
  // zero combT h-rows (h(0)=0), both batches
#pragma unroll
  for (int bb = 0; bb < 2; ++bb)
    for (int i = tid; i < 64 * 72; i += 256) combT[bb][64 * 72 + i] = (f16)0.f;

  // persistent fp32 hidden state (C-layout), per batch
  f32x4 h[2][4];
#pragma unroll
  for (int bb = 0; bb < 2; ++bb)
#pragma unroll
    for (int mt = 0; mt < 4; ++mt) h[bb][mt] = f32x4{0.f, 0.f, 0.f, 0.f};

  // prefetch t=0 inputs, per batch
  const float* xb[2];
  float4 xq0[2], xq1[2], xq2[2], xq3[2];
  float mCur[2], aCur[2], vtR[2];
  int lenm1[2];
#pragma unroll
  for (int bb = 0; bb < 2; ++bb) {
    xb[bb] = obs + (size_t)(b0 + bb) * T_ * (N_ * D_) + pn * D_ + pj;
    xq0[bb] = *(const float4*)(xb[bb]);
    xq1[bb] = *(const float4*)(xb[bb] + 4);
    xq2[bb] = *(const float4*)(xb[bb] + 8);
    xq3[bb] = *(const float4*)(xb[bb] + 12);
    mCur[bb] = 0.f; aCur[bb] = 0.f; vtR[bb] = 0.f;
    if (tid < N_) {
      vtR[bb] = vt[(b0 + bb) * N_ + tid];
      mCur[bb] = mask[(size_t)(b0 + bb) * T_ * N_ + tid];
      aCur[bb] = ai[(size_t)(b0 + bb) * T_ * N_ + tid];
    }
    lenm1[bb] = lengths[b0 + bb] - 1;
  }
  __syncthreads();

  f16x8 qh[4];
#pragma unroll
  for (int mt = 0; mt < 4; ++mt) qh[mt] = *(const f16x8*)(qvS + (lm + 16 * mt) * 8);

  for (int t = 0; t < T_; ++t) {
    // ---- P0: rs/mask + x staging (both batches) ----
#pragma unroll
    for (int bb = 0; bb < 2; ++bb) {
      if (tid < N_) {
        mS[bb][tid] = mCur[bb];
        rsS[bb][tid] = 0.5f * fast_tanh(aCur[bb] / (vtR[bb] + 1.f));
      }
      f16x8 v0 = {(f16)xq0[bb].x, (f16)xq0[bb].y, (f16)xq0[bb].z, (f16)xq0[bb].w,
                  (f16)xq1[bb].x, (f16)xq1[bb].y, (f16)xq1[bb].z, (f16)xq1[bb].w};
      f16x8 v1 = {(f16)xq2[bb].x, (f16)xq2[bb].y, (f16)xq2[bb].z, (f16)xq2[bb].w,
                  (f16)xq3[bb].x, (f16)xq3[bb].y, (f16)xq3[bb].z, (f16)xq3[bb].w};
      *(f16x8*)(xA[bb] + pn * 72 + pj) = v0;
      *(f16x8*)(xA[bb] + pn * 72 + pj + 8) = v1;
    }
    __syncthreads();  // B1: xA, rsS, mS visible

    // ---- P1: build A -> AP ; transpose x -> combT rows 0..63 (both) ----
    {
      f16x2 adjL[16];
      *(f16x8*)&adjL[0]  = *(const f16x8*)(adjS + pn * 64 + pj);
      *(f16x8*)&adjL[4]  = *(const f16x8*)(adjS + pn * 64 + pj + 4);
      *(f16x8*)&adjL[8]  = *(const f16x8*)(adjS + pn * 64 + pj + 8);
      *(f16x8*)&adjL[12] = *(const f16x8*)(adjS + pn * 64 + pj + 12);
#pragma unroll
      for (int bb = 0; bb < 2; ++bb) {
        float ri = rsS[bb][pn], mi = mS[bb][pn];
        f16x8 av0, av1;
#pragma unroll
        for (int k = 0; k < 16; ++k) {
          float a = ((float)adjL[k][0] -
                     (float)adjL[k][1] * fabsf(ri - rsS[bb][pj + k])) * mi * mS[bb][pj + k];
          if (pn == pj + k) a = 1.f;
          if (k < 8) av0[k] = (f16)a;
          else av1[k - 8] = (f16)a;
        }
        *(f16x8*)(AP[bb] + pn * 88 + pj) = av0;
        *(f16x8*)(AP[bb] + pn * 88 + pj + 8) = av1;

        // transpose: wave wv handles node block n0=16w, lane = feature d
        int n0 = 16 * wv;
        f16x8 t0, t1;
#pragma unroll
        for (int k = 0; k < 8; ++k) t0[k] = xA[bb][(n0 + k) * 72 + lane];
#pragma unroll
        for (int k = 0; k < 8; ++k) t1[k] = xA[bb][(n0 + 8 + k) * 72 + lane];
        *(f16x8*)(combT[bb] + lane * 72 + n0) = t0;
        *(f16x8*)(combT[bb] + lane * 72 + n0 + 8) = t1;
      }
    }
    __syncthreads();  // B2: AP, combT visible

    // ---- P2: msg = A @ [x;h] (8 MFMA-tiles/wave/batch) ; mr = A @ rs ----
#pragma unroll
    for (int bb = 0; bb < 2; ++bb) {
#pragma unroll
      for (int s = 0; s < 2; ++s) {
        int ft = 2 * wv + s;
#pragma unroll
        for (int mt = 0; mt < 4; ++mt) {
          f32x4 acc = {0.f, 0.f, 0.f, 0.f};
#pragma unroll
          for (int kt = 0; kt < 2; ++kt) {
            f16x8 aF = *(const f16x8*)(AP[bb] + (lm + 16 * mt) * 88 + 8 * lq + 32 * kt);
            f16x8 bF = *(const f16x8*)(combT[bb] + (lm + 16 * ft) * 72 + 8 * lq + 32 * kt);
            acc = __builtin_amdgcn_mfma_f32_16x16x32_f16(aF, bF, acc, 0, 0, 0);
          }
          int row = 16 * mt + 4 * lq;
          int col = 16 * ft + lm;
          actA[bb][(row + 0) * 168 + col] = (f16)acc[0];
          actA[bb][(row + 1) * 168 + col] = (f16)acc[1];
          actA[bb][(row + 2) * 168 + col] = (f16)acc[2];
          actA[bb][(row + 3) * 168 + col] = (f16)acc[3];
        }
      }
      f16x8 a0 = *(const f16x8*)(AP[bb] + pn * 88 + pj);
      f16x8 a1 = *(const f16x8*)(AP[bb] + pn * 88 + pj + 8);
      float s = 0.f;
#pragma unroll
      for (int k = 0; k < 8; ++k)
        s += (float)a0[k] * rsS[bb][pj + k] + (float)a1[k] * rsS[bb][pj + 8 + k];
      s += __shfl_xor(s, 1);
      s += __shfl_xor(s, 2);
      if ((tid & 3) == 0) mrS[bb][pn] = s;
    }
    __syncthreads();  // B3: actA(msg), mrS visible; AP free for h_r

    // ---- P3+P4 per batch (accumulators reused batch-sequentially) ----
    f16x2 upk[2][8], hrpk[2][8];
#pragma unroll
    for (int bb = 0; bb < 2; ++bb) {
      f32x4 racc[4], uacc[4];
#pragma unroll
      for (int mt = 0; mt < 4; ++mt) {
        racc[mt] = f32x4{0.f, 0.f, 0.f, 0.f};
        uacc[mt] = f32x4{0.f, 0.f, 0.f, 0.f};
      }
#pragma unroll
      for (int kt = 0; kt < 4; ++kt) {
        f16x8 aF[4];
#pragma unroll
        for (int mt = 0; mt < 4; ++mt)
          aF[mt] = *(const f16x8*)(actA[bb] + (lm + 16 * mt) * 168 + 8 * lq + 32 * kt);
#pragma unroll
        for (int q = 0; q < 5; ++q) {
#pragma unroll
          for (int mt = 0; mt < 4; ++mt) {
            f16x8 as = aF[mt] * splat8(qh[mt][q]);
            racc[mt] = __builtin_amdgcn_mfma_f32_16x16x32_f16(as, wW[0][kt][q], racc[mt], 0, 0, 0);
            uacc[mt] = __builtin_amdgcn_mfma_f32_16x16x32_f16(as, wW[1][kt][q], uacc[mt], 0, 0, 0);
          }
        }
      }
      // P4: elementwise r,u -> h_r ; write h_r into AP[bb]
#pragma unroll
      for (int mt = 0; mt < 4; ++mt) {
        float4 mr4 = *(const float4*)&mrS[bb][16 * mt + 4 * lq];
        float4 m4 = *(const float4*)&mS[bb][16 * mt + 4 * lq];
#pragma unroll
        for (int i = 0; i < 4; ++i) {
          int row = 16 * mt + 4 * lq + i;
          int ii = 2 * mt + (i >> 1);
          float pr = racc[mt][i] + (float)bR[ii][i & 1] + mr4[i] * (float)wRs[ii][i & 1];
          float pu = uacc[mt][i] + (float)bU[ii][i & 1] + mr4[i] * (float)wUs[ii][i & 1];
          float r = fast_sig(pr);
          float u = fast_sig(pu);
          float hr = (m4[i] > 0.f) ? r * h[bb][mt][i] : h[bb][mt][i];
          upk[bb][ii][i & 1] = (f16)u;
          hrpk[bb][ii][i & 1] = (f16)hr;
          AP[bb][row * 88 + oc] = (f16)hr;
        }
      }
      // prefetch next step inputs for this batch (covered by later phases)
      if (t + 1 < T_) {
        const float* xn = xb[bb] + (size_t)(t + 1) * (N_ * D_);
        xq0[bb] = *(const float4*)(xn);
        xq1[bb] = *(const float4*)(xn + 4);
        xq2[bb] = *(const float4*)(xn + 8);
        xq3[bb] = *(const float4*)(xn + 12);
        if (tid < N_) {
          mCur[bb] = mask[((size_t)(b0 + bb) * T_ + t + 1) * N_ + tid];
          aCur[bb] = ai[((size_t)(b0 + bb) * T_ + t + 1) * N_ + tid];
        }
      }
    }
    __syncthreads();  // B4: h_r (in AP) visible

    // ---- P5+P6 per batch ----
#pragma unroll
    for (int bb = 0; bb < 2; ++bb) {
      f32x4 cacc[4];
#pragma unroll
      for (int mt = 0; mt < 4; ++mt) cacc[mt] = f32x4{0.f, 0.f, 0.f, 0.f};
#pragma unroll
      for (int kt = 0; kt < 4; ++kt) {
        f16x8 aF[4];
#pragma unroll
        for (int mt = 0; mt < 4; ++mt) {
          if (kt < 2)
            aF[mt] = *(const f16x8*)(xA[bb] + (lm + 16 * mt) * 72 + 8 * lq + 32 * kt);
          else
            aF[mt] = *(const f16x8*)(AP[bb] + (lm + 16 * mt) * 88 + 8 * lq + 32 * (kt - 2));
        }
#pragma unroll
        for (int q = 0; q < 5; ++q) {
#pragma unroll
          for (int mt = 0; mt < 4; ++mt) {
            f16x8 as = aF[mt] * splat8(qh[mt][q]);
            cacc[mt] = __builtin_amdgcn_mfma_f32_16x16x32_f16(as, wW[2][kt][q], cacc[mt], 0, 0, 0);
          }
        }
      }
      // P6: candidate, h update, combT h-rows, output
#pragma unroll
      for (int mt = 0; mt < 4; ++mt) {
        float4 rs4 = *(const float4*)&rsS[bb][16 * mt + 4 * lq];
        float4 m4 = *(const float4*)&mS[bb][16 * mt + 4 * lq];
        f16x4 hq;
#pragma unroll
        for (int i = 0; i < 4; ++i) {
          int ii = 2 * mt + (i >> 1);
          float pc = cacc[mt][i] + (float)bC[ii][i & 1] + rs4[i] * (float)wCs[ii][i & 1];
          float cand = fast_tanh(pc);
          float u = (float)upk[bb][ii][i & 1];
          float hr = (float)hrpk[bb][ii][i & 1];
          float hn = (m4[i] > 0.f) ? (1.f - u) * hr + u * cand : h[bb][mt][i];
          h[bb][mt][i] = hn;
          hq[i] = (f16)hn;
        }
        *(f16x4*)(combT[bb] + (64 + oc) * 72 + 16 * mt + 4 * lq) = hq;
        if (t == lenm1[bb]) {
#pragma unroll
          for (int i = 0; i < 4; ++i)
            out[((size_t)(b0 + bb) * N_ + 16 * mt + 4 * lq + i) * D_ + oc] = h[bb][mt][i];
        }
      }
    }
    __syncthreads();  // B5: protect xA/rsS/mS/combT before next P0
  }
}

// ---------------------------------------------------------------------------
extern "C" void kernel_launch(void* const* d_in, const int* in_sizes, int n_in,
                              void* d_out, int out_size, void* d_ws, size_t ws_size,
                              hipStream_t stream) {
  const float* obs  = (const float*)d_in[0];
  const float* mask = (const float*)d_in[1];
  const int*   lens = (const int*)d_in[2];
  const float* ai   = (const float*)d_in[3];
  const float* vpr  = (const float*)d_in[4];
  const float* rarw = (const float*)d_in[5];
  const float* Wf1 = (const float*)d_in[6],  *bf1 = (const float*)d_in[7];
  const float* Wf2 = (const float*)d_in[8],  *bf2 = (const float*)d_in[9];
  const float* Wg1 = (const float*)d_in[10], *bg1 = (const float*)d_in[11];
  const float* Wg2 = (const float*)d_in[12], *bg2 = (const float*)d_in[13];
  const float* Wu = (const float*)d_in[14], *bu = (const float*)d_in[15];
  const float* Wr = (const float*)d_in[16], *br = (const float*)d_in[17];
  const float* Wc = (const float*)d_in[18], *bc = (const float*)d_in[19];

  char* p = (char*)d_ws;
  auto carve = [&](size_t bytes) {
    char* r = p;
    p += (bytes + 255) & ~(size_t)255;
    return r;
  };
  float* qv   = (float*)carve(N_ * Q_ * 4);
  float* neb  = (float*)carve(N_ * E_ * 4);
  f16x2* adjP = (f16x2*)carve(N_ * N_ * 4);
  float* brn  = (float*)carve(N_ * D_ * 4);
  float* bun  = (float*)carve(N_ * D_ * 4);
  float* bcn  = (float*)carve(N_ * D_ * 4);
  float* WrsR = (float*)carve(N_ * D_ * 4);
  float* WrsU = (float*)carve(N_ * D_ * 4);
  float* WrsC = (float*)carve(N_ * D_ * 4);
  float* vt   = (float*)carve(B_ * N_ * 4);
  f16* Wpk    = (f16*)carve((size_t)3 * 5 * 4 * 4 * 64 * 8 * 2);  // 245760 B

  k_mlps<<<N_, 256, 0, stream>>>(vpr, Wf1, bf1, Wf2, bf2, Wg1, bg1, Wg2, bg2, qv, neb);
  k_meta<<<N_, 64, 0, stream>>>(neb, qv, br, bu, bc, Wr, Wu, Wc, rarw,
                                adjP, brn, bun, bcn, WrsR, WrsU, WrsC);
  k_pack<<<240, 64, 0, stream>>>(Wr, Wu, Wc, Wpk);
  k_vt<<<B_, 64, 0, stream>>>(mask, vt);
  k_seq<<<B_ / 2, 256, 0, stream>>>(obs, mask, lens, ai, adjP,
                                    brn, bun, bcn, WrsR, WrsU, WrsC,
                                    qv, vt, Wpk, (float*)d_out);
}

// Round 9
// 1766.369 us; speedup vs baseline: 2.5470x; 2.5470x over previous
//
#include <hip/hip_runtime.h>
#include <cstddef>
#include <cstdint>

// Problem constants
#define B_ 64
#define T_ 128
#define N_ 64
#define D_ 64
#define Q_ 5
#define E_ 8
#define P_ 768
#define H_ 128

typedef _Float16 f16;
typedef _Float16 f16x2 __attribute__((ext_vector_type(2)));
typedef _Float16 f16x4 __attribute__((ext_vector_type(4)));
typedef _Float16 f16x8 __attribute__((ext_vector_type(8)));
typedef float f32x4 __attribute__((ext_vector_type(4)));

__device__ __forceinline__ float fast_sig(float x) {
  return 1.f / (1.f + __expf(-x));
}
__device__ __forceinline__ float fast_tanh(float x) {
  return 1.f - 2.f / (1.f + __expf(2.f * x));
}
__device__ __forceinline__ f16x8 splat8(f16 c) {
  return f16x8{c, c, c, c, c, c, c, c};
}

// ---------------------------------------------------------------------------
// K1: per-node MLPs -> qv (N,Q) and row-normalized ne (N,E). One block per n.
// ---------------------------------------------------------------------------
__global__ void k_mlps(const float* __restrict__ vpr,
                       const float* __restrict__ Wf1, const float* __restrict__ bf1,
                       const float* __restrict__ Wf2, const float* __restrict__ bf2,
                       const float* __restrict__ Wg1, const float* __restrict__ bg1,
                       const float* __restrict__ Wg2, const float* __restrict__ bg2,
                       float* __restrict__ qv, float* __restrict__ neb) {
  int n = blockIdx.x;
  int tid = threadIdx.x;  // 256
  __shared__ float v[P_];
  __shared__ float hf[H_];
  __shared__ float hg[H_];
  __shared__ float tmp[E_];

  for (int i = tid; i < P_; i += 256) v[i] = vpr[n * P_ + i];
  __syncthreads();

  if (tid < H_) {
    int j = tid;
    float a = bf1[j];
#pragma unroll 8
    for (int i = 0; i < P_; ++i) a += v[i] * Wf1[i * H_ + j];
    hf[j] = fmaxf(a, 0.f);
  } else {
    int j = tid - H_;
    float a = bg1[j];
#pragma unroll 8
    for (int i = 0; i < P_; ++i) a += v[i] * Wg1[i * H_ + j];
    hg[j] = fmaxf(a, 0.f);
  }
  __syncthreads();
  if (tid < Q_) {
    float a = bf2[tid];
    for (int j = 0; j < H_; ++j) a += hf[j] * Wf2[j * Q_ + tid];
    qv[n * Q_ + tid] = a;
  } else if (tid >= 8 && tid < 8 + E_) {
    int e = tid - 8;
    float a = bg2[e];
    for (int j = 0; j < H_; ++j) a += hg[j] * Wg2[j * E_ + e];
    tmp[e] = a;
  }
  __syncthreads();
  if (tid == 0) {
    float s = 0.f;
    for (int e = 0; e < E_; ++e) s += tmp[e] * tmp[e];
    float r = 1.f / sqrtf(s);
    for (int e = 0; e < E_; ++e) neb[n * E_ + e] = tmp[e] * r;
  }
}

// ---------------------------------------------------------------------------
// K2: adj row softmax -> adjP = f16x2{adj, adj*rarw}; per-node gate biases and
// rs-column weights (rank-1 fold of feature f=64). One block (64 thr) per n.
// ---------------------------------------------------------------------------
__global__ void k_meta(const float* __restrict__ neb, const float* __restrict__ qv,
                       const float* __restrict__ br, const float* __restrict__ bu,
                       const float* __restrict__ bc,
                       const float* __restrict__ Wr, const float* __restrict__ Wu,
                       const float* __restrict__ Wc, const float* __restrict__ rarw,
                       f16x2* __restrict__ adjP, float* __restrict__ brn,
                       float* __restrict__ bun, float* __restrict__ bcn,
                       float* __restrict__ WrsR, float* __restrict__ WrsU,
                       float* __restrict__ WrsC) {
  int n = blockIdx.x;
  int j = threadIdx.x;  // 64 = one wave
  float s = 0.f;
#pragma unroll
  for (int e = 0; e < E_; ++e) s += neb[n * E_ + e] * neb[j * E_ + e];
  float m = s;
  for (int off = 32; off; off >>= 1) m = fmaxf(m, __shfl_xor(m, off));
  float ex = __expf(s - m);
  float sum = ex;
  for (int off = 32; off; off >>= 1) sum += __shfl_xor(sum, off);
  float av = ex / sum;
  adjP[n * N_ + j] = f16x2{(f16)av, (f16)(av * rarw[n * N_ + j])};

  float pr = 0.f, pu = 0.f, pc = 0.f;
  float wr = 0.f, wu = 0.f, wc = 0.f;
#pragma unroll
  for (int q = 0; q < Q_; ++q) {
    float qq = qv[n * Q_ + q];
    pr += qq * br[q * D_ + j];
    pu += qq * bu[q * D_ + j];
    pc += qq * bc[q * D_ + j];
    wr += qq * Wr[((size_t)q * 129 + 64) * D_ + j];
    wu += qq * Wu[((size_t)q * 129 + 64) * D_ + j];
    wc += qq * Wc[((size_t)q * 129 + 64) * D_ + j];
  }
  brn[n * D_ + j] = pr;
  bun[n * D_ + j] = pu;
  bcn[n * D_ + j] = pc;
  WrsR[n * D_ + j] = wr;
  WrsU[n * D_ + j] = wu;
  WrsC[n * D_ + j] = wc;
}

// ---------------------------------------------------------------------------
// K3: pack shared gate weights into MFMA B-fragment order, fp16 (HW-verified
// in round 2 — do not change).
// frag id = ((g*5+q)*4+kt)*4+nt ; within frag lane l holds 8 f16:
//   B[k = 32*kt + 8*(l>>4) + e][col = 16*nt + (l&15)],  f = k + (k>=64)
// ---------------------------------------------------------------------------
__global__ void k_pack(const float* __restrict__ Wr, const float* __restrict__ Wu,
                       const float* __restrict__ Wc, f16* __restrict__ Wpk) {
  int bid = blockIdx.x;           // 240 = 3*5*4*4
  int nt = bid & 3;
  int kt = (bid >> 2) & 3;
  int q = (bid >> 4) % 5;
  int g = bid / 80;
  const float* W = (g == 0) ? Wr : ((g == 1) ? Wu : Wc);
  int l = threadIdx.x;            // 64
  int co = 16 * nt + (l & 15);
  f16* dst = Wpk + (size_t)bid * 512 + l * 8;
#pragma unroll
  for (int e = 0; e < 8; ++e) {
    int k = 32 * kt + 8 * (l >> 4) + e;
    int f = k + (k >= 64);
    dst[e] = (f16)W[((size_t)q * 129 + f) * D_ + co];
  }
}

// ---------------------------------------------------------------------------
// K4: var_total[b][n]
// ---------------------------------------------------------------------------
__global__ void k_vt(const float* __restrict__ mask, float* __restrict__ vt) {
  int b = blockIdx.x;
  int n = threadIdx.x;  // 64
  float s = 0.f;
  for (int t = 0; t < T_; ++t) s += mask[(b * T_ + t) * N_ + n];
  vt[b * N_ + n] = s;
}

// ---------------------------------------------------------------------------
// SEQ v10: r6's 4-wave/3-barrier pipeline (best, 1915 us) + REGISTER SLACK,
// LDS-budget-corrected. r8 failed compile: 80 c-frags = 81920 B (frag =
// 64 lanes x 8 f16 x 2 B = 1024 B, NOT 512 B) -> 165120 > 163840. v10
// splits: c-gate kt=0 stays in registers (wWc0, 20 VGPRs); kt=1..3 -> LDS
// (60 frags = 61440 B, compacted idx q*12 + (kt-1)*4 + nt). Frees 60 acc
// VGPRs (~70 slack) for the scheduler to batch ds_reads (r7 showed the
// stall is LDS-latency chains serialized by a full register file).
// LDS = 18432+18432+21504+22528+1024+512+512+256+61440 = 144640 <= 163840.
// Decision rule: >= 1870 us -> latency is structural; revert to r6, stop.
// ---------------------------------------------------------------------------
__global__ __launch_bounds__(256, 1) __attribute__((amdgpu_waves_per_eu(1, 1)))
void k_seq(const float* __restrict__ obs, const float* __restrict__ mask,
           const int* __restrict__ lengths, const float* __restrict__ ai,
           const f16x2* __restrict__ adjP,
           const float* __restrict__ brn, const float* __restrict__ bun,
           const float* __restrict__ bcn, const float* __restrict__ WrsR,
           const float* __restrict__ WrsU, const float* __restrict__ WrsC,
           const float* __restrict__ qv, const float* __restrict__ vt,
           const f16* __restrict__ Wpk, float* __restrict__ out) {
  // combT [feature k][node j] stride 72: rows 0..63 = x(d), 64..127 = h(d)
  __shared__ __align__(16) f16 combT[128 * 72];     // 18432 B
  __shared__ __align__(16) f16 xA[2][64 * 72];      // 18432 B  x row-major [n][d]
  __shared__ __align__(16) f16 actA[64 * 168];      // 21504 B  msg
  // AP[p] [i][j] stride 88: A-matrix (R1), then ALIASED as h_r [n][o] (R2..R3)
  __shared__ __align__(16) f16 AP[2][64 * 88];      // 22528 B
  __shared__ __align__(16) f16 qvS[64 * 8];         //  1024 B
  __shared__ __align__(16) float rsS[2][N_];
  __shared__ __align__(16) float mS[2][N_];
  __shared__ __align__(16) float mrS[N_];
  __shared__ __align__(16) f16 cWl[60 * 512];       // 61440 B c-gate kt=1..3

  const int tid = threadIdx.x;
  const int b = blockIdx.x;
  const int lane = tid & 63;
  const int wv = tid >> 6;        // 4 waves
  const int lm = lane & 15;
  const int lq = lane >> 4;
  const int oc = 16 * wv + lm;    // this wave's output column

  const int pn = tid >> 2;        // staging / A-build row (0..63)
  const int pj = 16 * (tid & 3);  // 16-wide j / d block

  // ---- persistent weight fragments: r,u [gate][kt][q] = 160 VGPRs ----
  f16x8 wW[2][4][5];
#pragma unroll
  for (int g = 0; g < 2; ++g)
#pragma unroll
    for (int kt = 0; kt < 4; ++kt)
#pragma unroll
      for (int q = 0; q < 5; ++q)
        wW[g][kt][q] = *(const f16x8*)(Wpk +
            ((size_t)(((g * 5 + q) * 4 + kt) * 4 + wv) * 64 + lane) * 8);

  // ---- c-gate kt=0 fragments in registers (20 VGPRs) ----
  f16x8 wWc0[5];
#pragma unroll
  for (int q = 0; q < 5; ++q)
    wWc0[q] = *(const f16x8*)(Wpk +
        ((size_t)(160 + 16 * q + wv) * 64 + lane) * 8);

  // ---- c-gate kt=1..3 -> LDS (60 frags, compacted q*12+(kt-1)*4+nt) ----
  for (int i = tid; i < 60 * 64; i += 256) {
    int fi = i >> 6, l = i & 63;
    int q = fi / 12, rem = fi % 12;
    int ktm1 = rem >> 2, nt = rem & 3;
    *(f16x8*)(cWl + ((size_t)fi * 64 + l) * 8) =
        *(const f16x8*)(Wpk +
            ((size_t)(160 + 16 * q + 4 * (ktm1 + 1) + nt) * 64 + l) * 8);
  }

  // ---- persistent biases / rs-fold weights (C-layout cells) ----
  f16x2 bR[8], bU[8], bC[8], wRs[8], wUs[8], wCs[8];
#pragma unroll
  for (int mt = 0; mt < 4; ++mt)
#pragma unroll
    for (int ii = 0; ii < 2; ++ii) {
      int n0 = 16 * mt + 4 * lq + 2 * ii;
      bR[2 * mt + ii]  = f16x2{(f16)brn[n0 * D_ + oc],  (f16)brn[(n0 + 1) * D_ + oc]};
      bU[2 * mt + ii]  = f16x2{(f16)bun[n0 * D_ + oc],  (f16)bun[(n0 + 1) * D_ + oc]};
      bC[2 * mt + ii]  = f16x2{(f16)bcn[n0 * D_ + oc],  (f16)bcn[(n0 + 1) * D_ + oc]};
      wRs[2 * mt + ii] = f16x2{(f16)WrsR[n0 * D_ + oc], (f16)WrsR[(n0 + 1) * D_ + oc]};
      wUs[2 * mt + ii] = f16x2{(f16)WrsU[n0 * D_ + oc], (f16)WrsU[(n0 + 1) * D_ + oc]};
      wCs[2 * mt + ii] = f16x2{(f16)WrsC[n0 * D_ + oc], (f16)WrsC[(n0 + 1) * D_ + oc]};
    }

  // ---- persistent adjacency for this thread's A cells ----
  f16x2 adjR[16];
#pragma unroll
  for (int k = 0; k < 16; ++k) adjR[k] = adjP[pn * N_ + pj + k];

  // ---- qv staging -> qh fragments ----
#pragma unroll
  for (int u2 = 0; u2 < 2; ++u2) {
    int idx = 2 * tid + u2;
    int n = idx >> 3, q = idx & 7;
    qvS[idx] = (q < Q_) ? (f16)qv[n * Q_ + q] : (f16)0.f;
  }
  // zero combT h-rows (h(0)=0)
  for (int i = tid; i < 64 * 72; i += 256) combT[64 * 72 + i] = (f16)0.f;

  // persistent fp32 hidden state (C-layout)
  f32x4 h[4];
#pragma unroll
  for (int mt = 0; mt < 4; ++mt) h[mt] = f32x4{0.f, 0.f, 0.f, 0.f};

  // ---- prologue: load + stage t=0 ----
  const float* xb = obs + (size_t)b * T_ * (N_ * D_) + pn * D_ + pj;
  {
    float4 x0 = *(const float4*)(xb);
    float4 x1 = *(const float4*)(xb + 4);
    float4 x2 = *(const float4*)(xb + 8);
    float4 x3 = *(const float4*)(xb + 12);
    f16x8 v0 = {(f16)x0.x, (f16)x0.y, (f16)x0.z, (f16)x0.w,
                (f16)x1.x, (f16)x1.y, (f16)x1.z, (f16)x1.w};
    f16x8 v1 = {(f16)x2.x, (f16)x2.y, (f16)x2.z, (f16)x2.w,
                (f16)x3.x, (f16)x3.y, (f16)x3.z, (f16)x3.w};
    *(f16x8*)(xA[0] + pn * 72 + pj) = v0;
    *(f16x8*)(xA[0] + pn * 72 + pj + 8) = v1;
  }
  float vtR = 0.f;
  if (tid < N_) {
    vtR = vt[b * N_ + tid];
    float mC = mask[(size_t)b * T_ * N_ + tid];
    float aC = ai[(size_t)b * T_ * N_ + tid];
    mS[0][tid] = mC;
    rsS[0][tid] = 0.5f * fast_tanh(aC / (vtR + 1.f));
  }
  const int lenm1 = lengths[b] - 1;
  __syncthreads();  // prologue stage visible

  f16x8 qh[4];
#pragma unroll
  for (int mt = 0; mt < 4; ++mt) qh[mt] = *(const f16x8*)(qvS + (lm + 16 * mt) * 8);

  // prologue: transpose x(0) -> combT x-rows ; A-build(0) -> AP[0]
  {
    int n0 = 16 * wv;
    f16x8 t0, t1;
#pragma unroll
    for (int k = 0; k < 8; ++k) t0[k] = xA[0][(n0 + k) * 72 + lane];
#pragma unroll
    for (int k = 0; k < 8; ++k) t1[k] = xA[0][(n0 + 8 + k) * 72 + lane];
    *(f16x8*)(combT + lane * 72 + n0) = t0;
    *(f16x8*)(combT + lane * 72 + n0 + 8) = t1;

    float ri = rsS[0][pn], mi = mS[0][pn];
    f16x8 av0, av1;
#pragma unroll
    for (int k = 0; k < 16; ++k) {
      float a = ((float)adjR[k][0] -
                 (float)adjR[k][1] * fabsf(ri - rsS[0][pj + k])) * mi * mS[0][pj + k];
      if (pn == pj + k) a = 1.f;
      if (k < 8) av0[k] = (f16)a;
      else av1[k - 8] = (f16)a;
    }
    *(f16x8*)(AP[0] + pn * 88 + pj) = av0;
    *(f16x8*)(AP[0] + pn * 88 + pj + 8) = av1;
  }
  __syncthreads();  // AP[0], combT ready

  for (int t = 0; t < T_; ++t) {
    const int cur = t & 1, nxt = cur ^ 1;

    // ==== R1: msg = A @ [x;h] (8 MFMA-tiles/wave) ; mr = A @ rs ====
    {
#pragma unroll
      for (int s = 0; s < 2; ++s) {
        int ft = 2 * wv + s;
#pragma unroll
        for (int mt = 0; mt < 4; ++mt) {
          f32x4 acc = {0.f, 0.f, 0.f, 0.f};
#pragma unroll
          for (int kt = 0; kt < 2; ++kt) {
            f16x8 aF = *(const f16x8*)(AP[cur] + (lm + 16 * mt) * 88 + 8 * lq + 32 * kt);
            f16x8 bF = *(const f16x8*)(combT + (lm + 16 * ft) * 72 + 8 * lq + 32 * kt);
            acc = __builtin_amdgcn_mfma_f32_16x16x32_f16(aF, bF, acc, 0, 0, 0);
          }
          int row = 16 * mt + 4 * lq;
          int col = 16 * ft + lm;
          actA[(row + 0) * 168 + col] = (f16)acc[0];
          actA[(row + 1) * 168 + col] = (f16)acc[1];
          actA[(row + 2) * 168 + col] = (f16)acc[2];
          actA[(row + 3) * 168 + col] = (f16)acc[3];
        }
      }
      f16x8 a0 = *(const f16x8*)(AP[cur] + pn * 88 + pj);
      f16x8 a1 = *(const f16x8*)(AP[cur] + pn * 88 + pj + 8);
      float s = 0.f;
#pragma unroll
      for (int k = 0; k < 8; ++k)
        s += (float)a0[k] * rsS[cur][pj + k] + (float)a1[k] * rsS[cur][pj + 8 + k];
      s += __shfl_xor(s, 1);
      s += __shfl_xor(s, 2);
      if ((tid & 3) == 0) mrS[pn] = s;
    }
    __syncthreads();  // BA: actA(msg), mrS visible; AP[cur] free for h_r

    // ==== R2: r,u GEMMs + elementwise -> h_r ; c x-half ; stage t+1 ====
    // issue next-step global loads early (latency hidden under the MFMAs)
    float4 nx0, nx1, nx2, nx3;
    float mN = 0.f, aN = 0.f;
    if (t + 1 < T_) {
      const float* xn = xb + (size_t)(t + 1) * (N_ * D_);
      nx0 = *(const float4*)(xn);
      nx1 = *(const float4*)(xn + 4);
      nx2 = *(const float4*)(xn + 8);
      nx3 = *(const float4*)(xn + 12);
      if (tid < N_) {
        mN = mask[((size_t)b * T_ + t + 1) * N_ + tid];
        aN = ai[((size_t)b * T_ + t + 1) * N_ + tid];
      }
    }
    // P3: r,u GEMMs (shared scaled A-fragments)
    f32x4 racc[4], uacc[4];
#pragma unroll
    for (int mt = 0; mt < 4; ++mt) {
      racc[mt] = f32x4{0.f, 0.f, 0.f, 0.f};
      uacc[mt] = f32x4{0.f, 0.f, 0.f, 0.f};
    }
#pragma unroll
    for (int kt = 0; kt < 4; ++kt) {
      f16x8 aF[4];
#pragma unroll
      for (int mt = 0; mt < 4; ++mt)
        aF[mt] = *(const f16x8*)(actA + (lm + 16 * mt) * 168 + 8 * lq + 32 * kt);
#pragma unroll
      for (int q = 0; q < 5; ++q) {
#pragma unroll
        for (int mt = 0; mt < 4; ++mt) {
          f16x8 as = aF[mt] * splat8(qh[mt][q]);
          racc[mt] = __builtin_amdgcn_mfma_f32_16x16x32_f16(as, wW[0][kt][q], racc[mt], 0, 0, 0);
          uacc[mt] = __builtin_amdgcn_mfma_f32_16x16x32_f16(as, wW[1][kt][q], uacc[mt], 0, 0, 0);
        }
      }
    }
    // P4: elementwise r,u -> h_r into AP[cur]
    f16x2 upk[8], hrpk[8];
    {
#pragma unroll
      for (int mt = 0; mt < 4; ++mt) {
        float4 mr4 = *(const float4*)&mrS[16 * mt + 4 * lq];
        float4 m4 = *(const float4*)&mS[cur][16 * mt + 4 * lq];
#pragma unroll
        for (int i = 0; i < 4; ++i) {
          int row = 16 * mt + 4 * lq + i;
          int ii = 2 * mt + (i >> 1);
          float pr = racc[mt][i] + (float)bR[ii][i & 1] + mr4[i] * (float)wRs[ii][i & 1];
          float pu = uacc[mt][i] + (float)bU[ii][i & 1] + mr4[i] * (float)wUs[ii][i & 1];
          float r = fast_sig(pr);
          float u = fast_sig(pu);
          float hr = (m4[i] > 0.f) ? r * h[mt][i] : h[mt][i];
          upk[ii][i & 1] = (f16)u;
          hrpk[ii][i & 1] = (f16)hr;
          AP[cur][row * 88 + oc] = (f16)hr;
        }
      }
    }
    // c-GEMM x-half (kt 0,1 — independent of h_r; kt0 regs, kt1 LDS)
    f32x4 cacc[4];
#pragma unroll
    for (int mt = 0; mt < 4; ++mt) cacc[mt] = f32x4{0.f, 0.f, 0.f, 0.f};
#pragma unroll
    for (int kt = 0; kt < 2; ++kt) {
      f16x8 aF[4];
#pragma unroll
      for (int mt = 0; mt < 4; ++mt)
        aF[mt] = *(const f16x8*)(xA[cur] + (lm + 16 * mt) * 72 + 8 * lq + 32 * kt);
#pragma unroll
      for (int q = 0; q < 5; ++q) {
        f16x8 wC = (kt == 0)
            ? wWc0[q]
            : *(const f16x8*)(cWl + ((size_t)(q * 12 + wv) * 64 + lane) * 8);
#pragma unroll
        for (int mt = 0; mt < 4; ++mt) {
          f16x8 as = aF[mt] * splat8(qh[mt][q]);
          cacc[mt] = __builtin_amdgcn_mfma_f32_16x16x32_f16(as, wC, cacc[mt], 0, 0, 0);
        }
      }
    }
    // stage t+1: x -> xA[nxt], rs/m -> [nxt]
    if (t + 1 < T_) {
      f16x8 v0 = {(f16)nx0.x, (f16)nx0.y, (f16)nx0.z, (f16)nx0.w,
                  (f16)nx1.x, (f16)nx1.y, (f16)nx1.z, (f16)nx1.w};
      f16x8 v1 = {(f16)nx2.x, (f16)nx2.y, (f16)nx2.z, (f16)nx2.w,
                  (f16)nx3.x, (f16)nx3.y, (f16)nx3.z, (f16)nx3.w};
      *(f16x8*)(xA[nxt] + pn * 72 + pj) = v0;
      *(f16x8*)(xA[nxt] + pn * 72 + pj + 8) = v1;
      if (tid < N_) {
        mS[nxt][tid] = mN;
        rsS[nxt][tid] = 0.5f * fast_tanh(aN / (vtR + 1.f));
      }
    }
    __syncthreads();  // BB: h_r (AP[cur]), xA[nxt], rs/m[nxt] visible

    // ==== R3: c h-half (kt 2,3 from LDS) + h update ; A-build(t+1) ;
    //      x-transpose(t+1) ====
#pragma unroll
    for (int kt = 0; kt < 2; ++kt) {
      f16x8 aF[4];
#pragma unroll
      for (int mt = 0; mt < 4; ++mt)
        aF[mt] = *(const f16x8*)(AP[cur] + (lm + 16 * mt) * 88 + 8 * lq + 32 * kt);
#pragma unroll
      for (int q = 0; q < 5; ++q) {
        f16x8 wC = *(const f16x8*)(cWl +
            ((size_t)(q * 12 + (kt + 1) * 4 + wv) * 64 + lane) * 8);
#pragma unroll
        for (int mt = 0; mt < 4; ++mt) {
          f16x8 as = aF[mt] * splat8(qh[mt][q]);
          cacc[mt] = __builtin_amdgcn_mfma_f32_16x16x32_f16(as, wC, cacc[mt], 0, 0, 0);
        }
      }
    }
    // P6: candidate, h update, combT h-rows, output
    {
#pragma unroll
      for (int mt = 0; mt < 4; ++mt) {
        float4 rs4 = *(const float4*)&rsS[cur][16 * mt + 4 * lq];
        float4 m4 = *(const float4*)&mS[cur][16 * mt + 4 * lq];
        f16x4 hq;
#pragma unroll
        for (int i = 0; i < 4; ++i) {
          int ii = 2 * mt + (i >> 1);
          float pc = cacc[mt][i] + (float)bC[ii][i & 1] + rs4[i] * (float)wCs[ii][i & 1];
          float cand = fast_tanh(pc);
          float u = (float)upk[ii][i & 1];
          float hr = (float)hrpk[ii][i & 1];
          float hn = (m4[i] > 0.f) ? (1.f - u) * hr + u * cand : h[mt][i];
          h[mt][i] = hn;
          hq[i] = (f16)hn;
        }
        *(f16x4*)(combT + (64 + oc) * 72 + 16 * mt + 4 * lq) = hq;
        if (t == lenm1) {
#pragma unroll
          for (int i = 0; i < 4; ++i)
            out[((size_t)b * N_ + 16 * mt + 4 * lq + i) * D_ + oc] = h[mt][i];
        }
      }
    }
    // A-build(t+1) -> AP[nxt] ; transpose x(t+1) -> combT x-rows
    if (t + 1 < T_) {
      float ri = rsS[nxt][pn], mi = mS[nxt][pn];
      f16x8 av0, av1;
#pragma unroll
      for (int k = 0; k < 16; ++k) {
        float a = ((float)adjR[k][0] -
                   (float)adjR[k][1] * fabsf(ri - rsS[nxt][pj + k])) * mi * mS[nxt][pj + k];
        if (pn == pj + k) a = 1.f;
        if (k < 8) av0[k] = (f16)a;
        else av1[k - 8] = (f16)a;
      }
      *(f16x8*)(AP[nxt] + pn * 88 + pj) = av0;
      *(f16x8*)(AP[nxt] + pn * 88 + pj + 8) = av1;

      int n0 = 16 * wv;
      f16x8 t0, t1;
#pragma unroll
      for (int k = 0; k < 8; ++k) t0[k] = xA[nxt][(n0 + k) * 72 + lane];
#pragma unroll
      for (int k = 0; k < 8; ++k) t1[k] = xA[nxt][(n0 + 8 + k) * 72 + lane];
      *(f16x8*)(combT + lane * 72 + n0) = t0;
      *(f16x8*)(combT + lane * 72 + n0 + 8) = t1;
    }
    __syncthreads();  // BC: combT(x,h), AP[nxt] ready for next R1
  }
}

// ---------------------------------------------------------------------------
extern "C" void kernel_launch(void* const* d_in, const int* in_sizes, int n_in,
                              void* d_out, int out_size, void* d_ws, size_t ws_size,
                              hipStream_t stream) {
  const float* obs  = (const float*)d_in[0];
  const float* mask = (const float*)d_in[1];
  const int*   lens = (const int*)d_in[2];
  const float* ai   = (const float*)d_in[3];
  const float* vpr  = (const float*)d_in[4];
  const float* rarw = (const float*)d_in[5];
  const float* Wf1 = (const float*)d_in[6],  *bf1 = (const float*)d_in[7];
  const float* Wf2 = (const float*)d_in[8],  *bf2 = (const float*)d_in[9];
  const float* Wg1 = (const float*)d_in[10], *bg1 = (const float*)d_in[11];
  const float* Wg2 = (const float*)d_in[12], *bg2 = (const float*)d_in[13];
  const float* Wu = (const float*)d_in[14], *bu = (const float*)d_in[15];
  const float* Wr = (const float*)d_in[16], *br = (const float*)d_in[17];
  const float* Wc = (const float*)d_in[18], *bc = (const float*)d_in[19];

  char* p = (char*)d_ws;
  auto carve = [&](size_t bytes) {
    char* r = p;
    p += (bytes + 255) & ~(size_t)255;
    return r;
  };
  float* qv   = (float*)carve(N_ * Q_ * 4);
  float* neb  = (float*)carve(N_ * E_ * 4);
  f16x2* adjP = (f16x2*)carve(N_ * N_ * 4);
  float* brn  = (float*)carve(N_ * D_ * 4);
  float* bun  = (float*)carve(N_ * D_ * 4);
  float* bcn  = (float*)carve(N_ * D_ * 4);
  float* WrsR = (float*)carve(N_ * D_ * 4);
  float* WrsU = (float*)carve(N_ * D_ * 4);
  float* WrsC = (float*)carve(N_ * D_ * 4);
  float* vt   = (float*)carve(B_ * N_ * 4);
  f16* Wpk    = (f16*)carve((size_t)3 * 5 * 4 * 4 * 64 * 8 * 2);  // 245760 B

  k_mlps<<<N_, 256, 0, stream>>>(vpr, Wf1, bf1, Wf2, bf2, Wg1, bg1, Wg2, bg2, qv, neb);
  k_meta<<<N_, 64, 0, stream>>>(neb, qv, br, bu, bc, Wr, Wu, Wc, rarw,
                                adjP, brn, bun, bcn, WrsR, WrsU, WrsC);
  k_pack<<<240, 64, 0, stream>>>(Wr, Wu, Wc, Wpk);
  k_vt<<<B_, 64, 0, stream>>>(mask, vt);
  k_seq<<<B_, 256, 0, stream>>>(obs, mask, lens, ai, adjP,
                                brn, bun, bcn, WrsR, WrsU, WrsC,
                                qv, vt, Wpk, (float*)d_out);
}